// Round 4
// baseline (27.679 us; speedup 1.0000x reference)
//
#include <hip/hip_runtime.h>
#include <hip/hip_bf16.h>
#include <math.h>

// scores[s] = sum_d E[s,d] * h[d]; out[s] = sigmoid(scores[s])
// 2048 blocks x 4 waves = 8192 waves; each wave owns 4 consecutive rows
// (16 KB contiguous). Rows processed in 2 pairs; pair i+1's 8 loads are
// issued BEFORE pair i's shuffle-reduce so the reduce hides load latency.
// Register budget kept under 64 VGPR to hold 8 waves/SIMD.

__device__ __forceinline__ float dot4(float4 a, float4 b) {
    return a.x * b.x + a.y * b.y + a.z * b.z + a.w * b.w;
}

__global__ __launch_bounds__(256, 8) void attn_matvec_sigmoid_pair(
        const float* __restrict__ h,
        const float* __restrict__ E,
        float* __restrict__ out,
        int seq_len, int d) {
    const int lane = threadIdx.x & 63;
    const int wave = blockIdx.x * (blockDim.x >> 6) + (threadIdx.x >> 6);

    const float4* __restrict__ hv = reinterpret_cast<const float4*>(h);
    const float4 h0 = hv[lane];
    const float4 h1 = hv[lane + 64];
    const float4 h2 = hv[lane + 128];
    const float4 h3 = hv[lane + 192];

    const int base = wave * 4;
    if (base >= seq_len) return;

    const float4* __restrict__ p =
        reinterpret_cast<const float4*>(E + (size_t)base * d);

    // ---- pair 0: rows base, base+1 (8 loads in flight) ----
    float4 a0 = p[lane],       a1 = p[lane + 64],  a2 = p[lane + 128], a3 = p[lane + 192];
    float4 b0 = p[lane + 256], b1 = p[lane + 320], b2 = p[lane + 384], b3 = p[lane + 448];

    float s0 = dot4(a0, h0) + dot4(a1, h1) + dot4(a2, h2) + dot4(a3, h3);
    float s1 = dot4(b0, h0) + dot4(b1, h1) + dot4(b2, h2) + dot4(b3, h3);

    // ---- issue pair 1 loads (rows base+2, base+3) before reducing pair 0 ----
    const float4* __restrict__ q = p + 512;
    a0 = q[lane];       a1 = q[lane + 64];  a2 = q[lane + 128]; a3 = q[lane + 192];
    b0 = q[lane + 256]; b1 = q[lane + 320]; b2 = q[lane + 384]; b3 = q[lane + 448];

    // ---- reduce pair 0 (two independent 6-step chains; hides pair-1 latency) ----
#pragma unroll
    for (int off = 32; off > 0; off >>= 1) {
        s0 += __shfl_xor(s0, off, 64);
        s1 += __shfl_xor(s1, off, 64);
    }

    // ---- pair 1 compute + reduce ----
    float s2 = dot4(a0, h0) + dot4(a1, h1) + dot4(a2, h2) + dot4(a3, h3);
    float s3 = dot4(b0, h0) + dot4(b1, h1) + dot4(b2, h2) + dot4(b3, h3);

#pragma unroll
    for (int off = 32; off > 0; off >>= 1) {
        s2 += __shfl_xor(s2, off, 64);
        s3 += __shfl_xor(s3, off, 64);
    }

    if (lane == 0) {
        float4 o;
        o.x = 1.0f / (1.0f + __expf(-s0));
        o.y = 1.0f / (1.0f + __expf(-s1));
        o.z = 1.0f / (1.0f + __expf(-s2));
        o.w = 1.0f / (1.0f + __expf(-s3));
        *reinterpret_cast<float4*>(out + base) = o;
    }
}

extern "C" void kernel_launch(void* const* d_in, const int* in_sizes, int n_in,
                              void* d_out, int out_size, void* d_ws, size_t ws_size,
                              hipStream_t stream) {
    const float* hidden = (const float*)d_in[0];   // [1024]
    const float* enc    = (const float*)d_in[1];   // [32768, 1024]
    float* out          = (float*)d_out;           // flat 32768

    const int d = in_sizes[0];        // 1024
    const int seq_len = out_size;     // 32768

    const int block = 256;                                   // 4 waves/block
    const int rows_per_wave = 4;
    const int waves_needed = (seq_len + rows_per_wave - 1) / rows_per_wave; // 8192
    const int grid = (waves_needed + 3) / 4;                 // 2048

    attn_matvec_sigmoid_pair<<<grid, block, 0, stream>>>(hidden, enc, out, seq_len, d);
}

// Round 5
// 24.381 us; speedup vs baseline: 1.1353x; 1.1353x over previous
//
#include <hip/hip_runtime.h>
#include <hip/hip_bf16.h>
#include <math.h>

// scores[s] = sum_d E[s,d] * h[d]; out[s] = sigmoid(scores[s])
// One 64-lane wave per 2 consecutive rows: 8 row loads + 4 h loads in
// flight, ~58 live VGPR -> natural 8 waves/SIMD (no forced cap, no spill).
// 16384 waves over 4096 blocks.

__device__ __forceinline__ float dot4(float4 a, float4 b) {
    return a.x * b.x + a.y * b.y + a.z * b.z + a.w * b.w;
}

__global__ __launch_bounds__(256) void attn_matvec_sigmoid2(
        const float* __restrict__ h,
        const float* __restrict__ E,
        float* __restrict__ out,
        int seq_len, int d) {
    const int lane = threadIdx.x & 63;
    const int wave = blockIdx.x * (blockDim.x >> 6) + (threadIdx.x >> 6);
    const int base = wave * 2;
    if (base >= seq_len) return;

    const float4* __restrict__ p =
        reinterpret_cast<const float4*>(E + (size_t)base * d);
    const float4* __restrict__ hv = reinterpret_cast<const float4*>(h);

    // 8 row loads (2 rows x 4 KiB) + 4 h loads (L1-resident) in flight
    float4 a0 = p[lane],       a1 = p[lane + 64];
    float4 a2 = p[lane + 128], a3 = p[lane + 192];
    float4 b0 = p[lane + 256], b1 = p[lane + 320];
    float4 b2 = p[lane + 384], b3 = p[lane + 448];
    float4 h0 = hv[lane],       h1 = hv[lane + 64];
    float4 h2 = hv[lane + 128], h3 = hv[lane + 192];

    float s0 = dot4(a0, h0) + dot4(a1, h1) + dot4(a2, h2) + dot4(a3, h3);
    float s1 = dot4(b0, h0) + dot4(b1, h1) + dot4(b2, h2) + dot4(b3, h3);

    // two independent 6-step butterfly chains, interleaved
#pragma unroll
    for (int off = 32; off > 0; off >>= 1) {
        s0 += __shfl_xor(s0, off, 64);
        s1 += __shfl_xor(s1, off, 64);
    }

    if (lane == 0) {
        float2 o;
        o.x = 1.0f / (1.0f + __expf(-s0));
        o.y = 1.0f / (1.0f + __expf(-s1));
        *reinterpret_cast<float2*>(out + base) = o;
    }
}

extern "C" void kernel_launch(void* const* d_in, const int* in_sizes, int n_in,
                              void* d_out, int out_size, void* d_ws, size_t ws_size,
                              hipStream_t stream) {
    const float* hidden = (const float*)d_in[0];   // [1024]
    const float* enc    = (const float*)d_in[1];   // [32768, 1024]
    float* out          = (float*)d_out;           // flat 32768

    const int d = in_sizes[0];        // 1024
    const int seq_len = out_size;     // 32768

    const int block = 256;                                 // 4 waves/block
    const int waves_needed = (seq_len + 1) / 2;            // 16384
    const int grid = (waves_needed + 3) / 4;               // 4096

    attn_matvec_sigmoid2<<<grid, block, 0, stream>>>(hidden, enc, out, seq_len, d);
}

// Round 6
// 23.761 us; speedup vs baseline: 1.1649x; 1.0261x over previous
//
#include <hip/hip_runtime.h>
#include <hip/hip_bf16.h>
#include <math.h>

// scores[s] = sum_d E[s,d] * h[d]; out[s] = sigmoid(scores[s])
// R5 structure (2 rows/wave, 8 row loads in flight, ~58 VGPR, 8 waves/SIMD)
// + NON-TEMPORAL loads on the zero-reuse E stream (nt flag: no cache
// allocate). h keeps normal cached loads (reused by every wave).

typedef float f32x4 __attribute__((ext_vector_type(4)));

__device__ __forceinline__ float dot4(f32x4 a, f32x4 b) {
    return a.x * b.x + a.y * b.y + a.z * b.z + a.w * b.w;
}

__global__ __launch_bounds__(256) void attn_matvec_sigmoid_nt(
        const float* __restrict__ h,
        const float* __restrict__ E,
        float* __restrict__ out,
        int seq_len, int d) {
    const int lane = threadIdx.x & 63;
    const int wave = blockIdx.x * (blockDim.x >> 6) + (threadIdx.x >> 6);
    const int base = wave * 2;
    if (base >= seq_len) return;

    const f32x4* __restrict__ p =
        reinterpret_cast<const f32x4*>(E + (size_t)base * d);
    const f32x4* __restrict__ hv = reinterpret_cast<const f32x4*>(h);

    // 8 streaming (non-temporal) row loads in flight
    f32x4 a0 = __builtin_nontemporal_load(&p[lane]);
    f32x4 a1 = __builtin_nontemporal_load(&p[lane + 64]);
    f32x4 a2 = __builtin_nontemporal_load(&p[lane + 128]);
    f32x4 a3 = __builtin_nontemporal_load(&p[lane + 192]);
    f32x4 b0 = __builtin_nontemporal_load(&p[lane + 256]);
    f32x4 b1 = __builtin_nontemporal_load(&p[lane + 320]);
    f32x4 b2 = __builtin_nontemporal_load(&p[lane + 384]);
    f32x4 b3 = __builtin_nontemporal_load(&p[lane + 448]);

    // h: normal cached loads (L1-resident, reused chip-wide)
    f32x4 h0 = hv[lane];
    f32x4 h1 = hv[lane + 64];
    f32x4 h2 = hv[lane + 128];
    f32x4 h3 = hv[lane + 192];

    float s0 = dot4(a0, h0) + dot4(a1, h1) + dot4(a2, h2) + dot4(a3, h3);
    float s1 = dot4(b0, h0) + dot4(b1, h1) + dot4(b2, h2) + dot4(b3, h3);

#pragma unroll
    for (int off = 32; off > 0; off >>= 1) {
        s0 += __shfl_xor(s0, off, 64);
        s1 += __shfl_xor(s1, off, 64);
    }

    if (lane == 0) {
        float2 o;
        o.x = 1.0f / (1.0f + __expf(-s0));
        o.y = 1.0f / (1.0f + __expf(-s1));
        *reinterpret_cast<float2*>(out + base) = o;
    }
}

extern "C" void kernel_launch(void* const* d_in, const int* in_sizes, int n_in,
                              void* d_out, int out_size, void* d_ws, size_t ws_size,
                              hipStream_t stream) {
    const float* hidden = (const float*)d_in[0];   // [1024]
    const float* enc    = (const float*)d_in[1];   // [32768, 1024]
    float* out          = (float*)d_out;           // flat 32768

    const int d = in_sizes[0];        // 1024
    const int seq_len = out_size;     // 32768

    const int block = 256;                                 // 4 waves/block
    const int waves_needed = (seq_len + 1) / 2;            // 16384
    const int grid = (waves_needed + 3) / 4;               // 4096

    attn_matvec_sigmoid_nt<<<grid, block, 0, stream>>>(hidden, enc, out, seq_len, d);
}